// Round 11
// baseline (246.861 us; speedup 1.0000x reference)
//
#include <hip/hip_runtime.h>
#include <hip/hip_fp16.h>

// Problem constants (from reference)
#define N_SAMPLES 524288
#define N_FEATURES 64
#define N_GATES 64
#define N_OUTPUTS 8
#define BASE_COLS 66          // N_FEATURES + 2 (zero col, one col)
#define MAX_CONN 130          // BASE + N_GATES

#define CH 8                  // gates per round
#define MAXSLOTS 512          // worst case: 64 levels x 8 padded slots
#define GWS_STR 131           // plan LDS stride for gate weights
#define NW 128                // circuit threads (2 waves), one half2 word each
#define TPB 256               // samples per circuit block
#define STR 129               // circuit LDS row stride in half2 words (odd)
// pad slot: reads const0 row (64), writes dummy row 130, weight row 64 (zeros)
#define PAD_SLOT (64 | (64 << 8) | (130 << 16) | (64 << 24))

typedef float v2f __attribute__((ext_vector_type(2)));

// ---------------------------------------------------------------------------
// top-2 insert, tie-break lower index (matches jax.lax.top_k stable order)
// ---------------------------------------------------------------------------
__device__ __forceinline__ void top2_ins(float x, int j, float& v1, int& i1, float& v2, int& i2) {
    bool gt1 = (x > v1) || (x == v1 && j < i1);
    bool gt2 = (x > v2) || (x == v2 && j < i2);
    if (gt1) { v2 = v1; i2 = i1; v1 = x; i1 = j; }
    else if (gt2) { v2 = x; i2 = j; }
}

// ---------------------------------------------------------------------------
// Kernel 1: plan (256 threads; proven in rounds 8/9). Top-2 per gate
// (strip-parallel), dataflow levels (shfl relaxation), then ONE level-ordered
// slot table, each level padded to a multiple of 8 (rounds never span levels
// -> slots within a round are independent -> circuit batches 16 reads before
// any write of the round):
//   slot = row_a | row_b<<8 | row_wr<<16 | weightRow<<24
// Row space: 0-63 features, 64 const0, 65 const1, 66+g gate g, 130 dummy.
// Pads: PAD_SLOT (weight row 64 = zeros -> contributes nothing, branchless).
// Also emits wS[65][8] (= ow with a zero row appended) and nrounds.
// ---------------------------------------------------------------------------
__global__ __launch_bounds__(256) void plan_kernel(
    const float* __restrict__ gw,
    const float* __restrict__ ow,
    int*   __restrict__ tab,     // [MAXSLOTS]
    float* __restrict__ wS,      // [65][8]
    int*   __restrict__ nrp)
{
    __shared__ float gws[N_GATES * GWS_STR];            // 33,536 B
    __shared__ float pv1[4][N_GATES], pv2[4][N_GATES];  // 2 KB
    __shared__ int   pi1[4][N_GATES], pi2[4][N_GATES];  // 2 KB
    __shared__ int   tabL[MAXSLOTS];                    // 2 KB

    const int tid = threadIdx.x;

    // ---- stage 64x130 gate weights, vectorized + coalesced
    const float4* gw4 = (const float4*)gw;              // 2080 float4s
    for (int k = tid; k < (N_GATES * MAX_CONN) / 4; k += 256) {
        float4 v = gw4[k];
        int base = 4 * k;
        #pragma unroll
        for (int e = 0; e < 4; ++e) {
            int idx = base + e;
            int gi  = idx / MAX_CONN;
            int jj  = idx - gi * MAX_CONN;
            gws[gi * GWS_STR + jj] = (&v.x)[e];
        }
    }
    __syncthreads();

    // ---- partial top-2: thread (gate g, strip s), ~33 columns each
    {
        const int g = tid & 63, s = tid >> 6;
        const int avail = BASE_COLS + g;
        int j0 = s * 33;
        int j1 = j0 + 33; if (j1 > avail) j1 = avail;
        float v1 = -1e30f, v2 = -1e30f;
        int   i1 = 0x7fffffff, i2 = 0x7fffffff;
        const float* w = gws + g * GWS_STR;
        for (int j = j0; j < j1; ++j)
            top2_ins(w[j], j, v1, i1, v2, i2);
        pv1[s][g] = v1; pi1[s][g] = i1;
        pv2[s][g] = v2; pi2[s][g] = i2;
    }
    __syncthreads();

    if (tid >= 64) return;              // wave 0 finishes alone (no barriers below)
    const int l = tid;                  // lane == gate id

    // ---- merge strip partials
    float v1 = -1e30f, v2 = -1e30f;
    int   i1 = 0x7fffffff, i2 = 0x7fffffff;
    #pragma unroll
    for (int s = 0; s < 4; ++s) {
        top2_ins(pv1[s][l], pi1[s][l], v1, i1, v2, i2);
        top2_ins(pv2[s][l], pi2[s][l], v1, i1, v2, i2);
    }

    // ---- dataflow level: parallel relaxation (preds have smaller gate id)
    const bool ga = (i1 >= BASE_COLS), gb = (i2 >= BASE_COLS);
    const int  pa = ga ? (i1 - BASE_COLS) : 0;
    const int  pb = gb ? (i2 - BASE_COLS) : 0;
    int lvl = 0;
    bool changed = true;
    while (__any(changed)) {
        int la = __shfl(lvl, pa);
        int lb = __shfl(lvl, pb);
        int nl = lvl;
        if (ga && la + 1 > nl) nl = la + 1;
        if (gb && lb + 1 > nl) nl = lb + 1;
        changed = (nl != lvl);
        lvl = nl;
    }

    // ---- emission: level order, each level padded to a multiple of CH
    int base = 0, assigned = 0, myslot = 0;
    for (int L = 0; L < 64 && assigned < 64; ++L) {
        unsigned long long mask = __ballot(lvl == L);
        int c = __popcll(mask);
        if (!c) continue;
        if (lvl == L) {
            int r = __popcll(mask & ((1ull << l) - 1ull));
            myslot = base + r;
        }
        int cpad = (c + CH - 1) & ~(CH - 1);
        if (l < cpad - c) tabL[base + c + l] = PAD_SLOT;   // pads for this level
        base += cpad;
        assigned += c;
    }
    // real slot (disjoint from pad indices; same-wave DS is in-order)
    tabL[myslot] = i1 | (i2 << 8) | ((BASE_COLS + l) << 16) | (l << 24);

    // ---- copy out table, weights (+ zero row 64), round count
    for (int q = l; q < base; q += 64) tab[q] = tabL[q];
    for (int q = l; q < 65 * N_OUTPUTS; q += 64)
        wS[q] = (q < N_GATES * N_OUTPUTS) ? ow[q] : 0.0f;
    if (l == 0) *nrp = base / CH;
}

// ---------------------------------------------------------------------------
// Kernel 2: circuit — the 217.3-champion structure + level-batched rounds.
// 128 threads (2 waves), 256 samples/block, thread owns ONE half2 word
// (samples 2t, 2t+1). LDS = 131 rows x stride 129 = 67,596 B -> 2 blocks/CU.
// ONE barrier total (after staging); gate columns are thread-private, so the
// round loop is barrier-free and same-wave DS order guarantees RAW.
// Per round: 8 slots via uniform s_loads -> 16 independent ds_read_b32
// (same-level gates: reads provably precede round writes) -> 8 hfma2 ->
// 8 ds_write_b32 -> 64 pk_fma inline GEMV. ~13 rounds vs champion's 64
// serial gates: the dependent-DS chain shrinks ~5x; everything else equal.
// ---------------------------------------------------------------------------
__global__ __launch_bounds__(NW) void circuit_kernel(
    const float* __restrict__ X,
    const int*   __restrict__ tab,     // [MAXSLOTS] level-ordered slots
    const float* __restrict__ wS,      // [65][8] weights + zero row
    const int*   __restrict__ nrp,
    const float* __restrict__ scale,   // [8]
    float*       __restrict__ out)     // [N_SAMPLES][8]
{
    __shared__ __half2 buf[131 * STR];   // 67,596 B

    const int t = threadIdx.x;           // 0..127
    const long long s0 = (long long)blockIdx.x * TPB;

    // ---- stage X chunk (256 samples x 64 feats), champion's exact pattern:
    // iter k, thread t: q = k*128+t, c4 = q&15 (float4 col), j = q>>4 (word).
    const float4* Xv = (const float4*)(X + s0 * N_FEATURES);
    #pragma unroll
    for (int k = 0; k < 16; ++k) {
        int q  = k * NW + t;
        int c4 = q & 15;
        int j  = q >> 4;
        float4 va = Xv[(2 * j)     * 16 + c4];
        float4 vb = Xv[(2 * j + 1) * 16 + c4];
        int c = 4 * c4;
        buf[(c + 0) * STR + j] = __halves2half2(__float2half(va.x), __float2half(vb.x));
        buf[(c + 1) * STR + j] = __halves2half2(__float2half(va.y), __float2half(vb.y));
        buf[(c + 2) * STR + j] = __halves2half2(__float2half(va.z), __float2half(vb.z));
        buf[(c + 3) * STR + j] = __halves2half2(__float2half(va.w), __float2half(vb.w));
    }
    buf[64 * STR + t] = __half2half2(__float2half(0.0f));   // const0 row
    buf[65 * STR + t] = __half2half2(__float2half(1.0f));   // const1 row
    __syncthreads();                     // the only barrier

    const int nr = *nrp;                 // uniform -> s_load
    const __half2 one2 = __half2half2(__float2half(1.0f));

    v2f acc[N_OUTPUTS];
    #pragma unroll
    for (int o = 0; o < N_OUTPUTS; ++o) { acc[o].x = 0.0f; acc[o].y = 0.0f; }

    for (int r = 0; r < nr; ++r) {
        // 8 slot words, uniform addresses -> scalar loads (off the DS chain)
        int sv[CH];
        #pragma unroll
        for (int k = 0; k < CH; ++k) sv[k] = tab[r * CH + k];

        // ---- 16 independent reads, all issued before any write of the round
        __half2 A[CH], B[CH];
        #pragma unroll
        for (int k = 0; k < CH; ++k) {
            A[k] = buf[(sv[k] & 255) * STR + t];
            B[k] = buf[((sv[k] >> 8) & 255) * STR + t];
        }

        // ---- compute + write + inline GEMV (pads: dummy row 130, zero weights)
        #pragma unroll
        for (int k = 0; k < CH; ++k) {
            __half2 gv = __hfma2(__hneg2(A[k]), B[k], one2);     // 1 - a*b
            buf[((sv[k] >> 16) & 255) * STR + t] = gv;
            v2f g2; g2.x = __low2float(gv); g2.y = __high2float(gv);
            const float* wp = wS + ((sv[k] >> 24) & 255) * N_OUTPUTS;  // s_load
            #pragma unroll
            for (int o = 0; o < N_OUTPUTS; ++o) {
                v2f wv; wv.x = wp[o]; wv.y = wp[o];
                acc[o] = __builtin_elementwise_fma(g2, wv, acc[o]);    // v_pk_fma_f32
            }
        }
    }

    // ---- epilogue: scale + coalesced store (64 B/lane), champion's exact form
    float sc[N_OUTPUTS];
    #pragma unroll
    for (int o = 0; o < N_OUTPUTS; ++o) sc[o] = scale[o];

    float4* outv = (float4*)(out + (s0 + 2 * t) * N_OUTPUTS);
    outv[0] = make_float4(acc[0].x * sc[0], acc[1].x * sc[1], acc[2].x * sc[2], acc[3].x * sc[3]);
    outv[1] = make_float4(acc[4].x * sc[4], acc[5].x * sc[5], acc[6].x * sc[6], acc[7].x * sc[7]);
    outv[2] = make_float4(acc[0].y * sc[0], acc[1].y * sc[1], acc[2].y * sc[2], acc[3].y * sc[3]);
    outv[3] = make_float4(acc[4].y * sc[4], acc[5].y * sc[5], acc[6].y * sc[6], acc[7].y * sc[7]);
}

extern "C" void kernel_launch(void* const* d_in, const int* in_sizes, int n_in,
                              void* d_out, int out_size, void* d_ws, size_t ws_size,
                              hipStream_t stream_)
{
    const float* X     = (const float*)d_in[0];  // [524288][64]
    const float* gw    = (const float*)d_in[1];  // [64][130]
    const float* ow    = (const float*)d_in[2];  // [64][8]
    const float* scale = (const float*)d_in[3];  // [8]
    float* out = (float*)d_out;                  // [524288][8]

    char* ws = (char*)d_ws;
    int*   tab = (int*)ws;                       // 512*4 = 2048 B
    float* wS  = (float*)(ws + 2048);            // 65*8*4 = 2080 B
    int*   nrp = (int*)(ws + 2048 + 2080 + 32);  // 4 B (aligned past wS)

    plan_kernel<<<1, 256, 0, stream_>>>(gw, ow, tab, wS, nrp);

    const int blocks = N_SAMPLES / TPB;          // 2048
    circuit_kernel<<<blocks, NW, 0, stream_>>>(X, tab, wS, nrp, scale, out);
}